// Round 4
// baseline (169.609 us; speedup 1.0000x reference)
//
#include <hip/hip_runtime.h>
#include <stdint.h>

#define ALPHA 0.2f
#define NEG_BIG -9000000000000000.0f
#define L2E 1.4426950408889634f

typedef __attribute__((ext_vector_type(8))) short bf16x8;
typedef __attribute__((ext_vector_type(8))) unsigned short u16x8;
typedef __attribute__((ext_vector_type(4))) float f32x4;

__device__ __forceinline__ unsigned short f2bf(float f) {
    unsigned int u = __float_as_uint(f);
    u += 0x7fffu + ((u >> 16) & 1u);   // RNE
    return (unsigned short)(u >> 16);
}

__device__ __forceinline__ void gload_lds16(const void* g, void* l) {
    __builtin_amdgcn_global_load_lds(
        (const __attribute__((address_space(1))) unsigned int*)g,
        (__attribute__((address_space(3))) unsigned int*)l, 16, 0, 0);
}

// ---------------------------------------------------------------------------
// Blocks 0..255: Wtbf[o*256+t] = bf16(W[t*256+o]).
// Block 256:     wa[k] = W[k,:]·a_l ; wa[256+k] = W[k,:]·a_r  (fp32).
// ---------------------------------------------------------------------------
__global__ void wt_wa_kernel(const float* __restrict__ W,
                             const float* __restrict__ a,
                             unsigned short* __restrict__ Wtbf,
                             float* __restrict__ wa) {
    const int t = threadIdx.x;
    if (blockIdx.x < 256) {
        const int o = blockIdx.x;
        Wtbf[o * 256 + t] = f2bf(W[t * 256 + o]);
    } else {
        float sl = 0.f, sr = 0.f;
        const float* wr = W + t * 256;
        for (int o = 0; o < 256; ++o) {
            const float wv = wr[o];
            sl += wv * a[o];
            sr += wv * a[256 + o];
        }
        wa[t] = sl;
        wa[256 + t] = sr;
    }
}

// ---------------------------------------------------------------------------
// One wave per row r: el2[r] = (x[r,:]·wa_l)*log2(e), er2 likewise,
// and xbf[r,:] = bf16(x[r,:]).
// ---------------------------------------------------------------------------
__global__ __launch_bounds__(256) void eler2x_kernel(
    const float* __restrict__ x, const float* __restrict__ wa,
    float* __restrict__ el, float* __restrict__ er,
    unsigned short* __restrict__ xbf)
{
    const int w = threadIdx.x >> 6, l = threadIdx.x & 63;
    const int r = blockIdx.x * 4 + w;       // 0..16383
    const float4 xv = *(const float4*)(x + (size_t)r * 256 + l * 4);
    const float4 al = *(const float4*)(wa + l * 4);
    const float4 ar = *(const float4*)(wa + 256 + l * 4);

    ushort4 xb;
    xb.x = f2bf(xv.x); xb.y = f2bf(xv.y); xb.z = f2bf(xv.z); xb.w = f2bf(xv.w);
    *(ushort4*)(xbf + (size_t)r * 256 + l * 4) = xb;

    float sl = xv.x * al.x + xv.y * al.y + xv.z * al.z + xv.w * al.w;
    float sr = xv.x * ar.x + xv.y * ar.y + xv.z * ar.z + xv.w * ar.w;
#pragma unroll
    for (int off = 32; off >= 1; off >>= 1) {
        sl += __shfl_xor(sl, off);
        sr += __shfl_xor(sr, off);
    }
    if (l == 0) { el[r] = sl * L2E; er[r] = sr * L2E; }
}

// ---------------------------------------------------------------------------
// h_T (256 x 16384) = Wtbf (256x256) @ xbf^T.  Flat batched GEMM.
// 64(m) x 128(n) tiles, K-step 64, grid (128,4) = 512 blocks (2/CU).
// 2-phase: double-buffered LDS, counted vmcnt (loads fly across barriers).
// ---------------------------------------------------------------------------
__global__ __launch_bounds__(256) void gemm_h(
    const unsigned short* __restrict__ A,    // Wtbf 256x256
    const unsigned short* __restrict__ Bt,   // xbf 16384x256
    unsigned short* __restrict__ C)          // h_T 256x16384
{
    __shared__ __align__(16) unsigned short As[2 * 64 * 64];    // 16 KB
    __shared__ __align__(16) unsigned short Bs[2 * 128 * 64];   // 32 KB

    const int tid = threadIdx.x;
    const int w = tid >> 6, l = tid & 63;
    const int q = l >> 4, ml = l & 15;
    const int wm = (w >> 1) * 32;
    const int wn = (w & 1) * 64;
    const int m0 = blockIdx.y * 64;
    const int n0 = blockIdx.x * 128;

    f32x4 acc[2][4];
#pragma unroll
    for (int i = 0; i < 2; ++i)
#pragma unroll
        for (int j = 0; j < 4; ++j) {
            f32x4 z = {0.f, 0.f, 0.f, 0.f};
            acc[i][j] = z;
        }

#define GSTAGE(BI, K0) do {                                                   \
    _Pragma("unroll")                                                         \
    for (int c_ = 0; c_ < 2; ++c_) {                                          \
        const int cb_ = c_ * 256 + (w << 6);                                  \
        const int p_ = cb_ + l;                                               \
        const int r_ = p_ >> 3;                                               \
        const int cc_ = (p_ & 7) ^ (r_ & 7);                                  \
        gload_lds16(A + (size_t)(m0 + r_) * 256 + (K0) + cc_ * 8,             \
                    As + (BI) * 4096 + cb_ * 8);                              \
    }                                                                         \
    _Pragma("unroll")                                                         \
    for (int c_ = 0; c_ < 4; ++c_) {                                          \
        const int cb_ = c_ * 256 + (w << 6);                                  \
        const int p_ = cb_ + l;                                               \
        const int r_ = p_ >> 3;                                               \
        const int cc_ = (p_ & 7) ^ (r_ & 7);                                  \
        gload_lds16(Bt + (size_t)(n0 + r_) * 256 + (K0) + cc_ * 8,            \
                    Bs + (BI) * 8192 + cb_ * 8);                              \
    } } while (0)

    GSTAGE(0, 0);

    for (int s = 0; s < 4; ++s) {
        const int cur = s & 1;
        if (s + 1 < 4) {
            GSTAGE((s + 1) & 1, (s + 1) * 64);
            asm volatile("s_waitcnt vmcnt(6) lgkmcnt(0)" ::: "memory");
        } else {
            asm volatile("s_waitcnt vmcnt(0) lgkmcnt(0)" ::: "memory");
        }
        __builtin_amdgcn_s_barrier();
        __builtin_amdgcn_sched_barrier(0);

        const unsigned short* Ab = As + cur * 4096;
        const unsigned short* Bb = Bs + cur * 8192;
        bf16x8 aF[2][2], bF[2][4];
#pragma unroll
        for (int ks = 0; ks < 2; ++ks) {
#pragma unroll
            for (int mt = 0; mt < 2; ++mt) {
                const int mm = wm + mt * 16 + ml;
                aF[ks][mt] = *(const bf16x8*)(Ab + (mm * 8 + ((ks * 4 + q) ^ (mm & 7))) * 8);
            }
#pragma unroll
            for (int nt = 0; nt < 4; ++nt) {
                const int nn = wn + nt * 16 + ml;
                bF[ks][nt] = *(const bf16x8*)(Bb + (nn * 8 + ((ks * 4 + q) ^ (nn & 7))) * 8);
            }
        }
#pragma unroll
        for (int ks = 0; ks < 2; ++ks)
            for (int mt = 0; mt < 2; ++mt)
                for (int nt = 0; nt < 4; ++nt)
                    acc[mt][nt] = __builtin_amdgcn_mfma_f32_16x16x32_bf16(
                        aF[ks][mt], bF[ks][nt], acc[mt][nt], 0, 0, 0);

        asm volatile("s_waitcnt lgkmcnt(0)" ::: "memory");
        __builtin_amdgcn_s_barrier();
    }
#undef GSTAGE

    for (int mt = 0; mt < 2; ++mt)
        for (int nt = 0; nt < 4; ++nt) {
            const int gn = n0 + wn + nt * 16 + ml;
            for (int r = 0; r < 4; ++r) {
                const int gm = m0 + wm + mt * 16 + q * 4 + r;
                C[(size_t)gm * 16384 + gn] = f2bf(acc[mt][nt][r]);
            }
        }
}

// ---------------------------------------------------------------------------
// FUSED mask + PV: out[b, i0..i0+63, :] = softmax(mask(e)) @ h[b].
// Grid 256 (1/CU), 512 threads (8 waves: 2m x 4n).
//
// Thread <-> work mapping (IDENTICAL in both phases): thread t owns row
// ib = t>>3 and cols {js + 32k, k=0..31}, js = (t&7)*4.
//   Phase 1: stream adj[rg, :] (int4 per k), online base-2 logsumexp with
//     chunk-max (5 exp2 / 4 cols), adjacency bits -> 4 REGISTERS (mw[4],
//     bit (k&7)*4+u of word k>>3).  8-lane shfl combine -> c_s[64] in LDS.
//     No pk16 / c arrays, no second adj pass, no separate kernel.
//   Phase 2: round-3's proven 2-phase j-loop (Hs dbuf via global_load_lds,
//     counted vmcnt(2), raw barriers), P rebuilt from mw regs + er_s + c_s.
//     t-loop fully unrolled -> mw[] indices static (no scratch).
// First Hs stage issued BEFORE phase 1 -> its latency hides under the
// ~10.6 us adj read.  XCD decode: b = ((bid&7)<<1)|(slot>>4).
// ---------------------------------------------------------------------------
__global__ __launch_bounds__(512) void maskpv_kernel(
    const int* __restrict__ adj,
    const float* __restrict__ el2,
    const float* __restrict__ er2,
    const unsigned short* __restrict__ hT,   // 256 x 16384 (row stride 16384)
    float* __restrict__ out)
{
    __shared__ float er_s[1024];                                  //  4 KB
    __shared__ float c_s[64];
    __shared__ __align__(16) unsigned short Hs[2 * 256 * 32];     // 32 KB
    __shared__ __align__(16) unsigned short Ps[2 * 64 * 40];      // 10 KB

    const int tid = threadIdx.x;
    const int w = tid >> 6, l = tid & 63;
    const int q = l >> 4, ml = l & 15;
    const int wm = (w >> 2) * 32;       // 0 | 32
    const int wn = (w & 3) * 64;        // 0..192

    const int bid = blockIdx.x;
    const int slot = bid >> 3;                        // 0..31
    const int b = ((bid & 7) << 1) | (slot >> 4);     // 2 batches per XCD
    const int i0 = (slot & 15) * 64;

    const int ib = tid >> 3;            // my row (0..63)
    const int js = (tid & 7) * 4;       // my col offset within 32-chunk
    const int rg = (b << 10) + i0 + ib;
    const float el2i = el2[rg];

    const unsigned short* hb = hT + (size_t)b * 1024;

// stage 16 KB: 1024 chunks of 16B, 512 threads -> 2 gload/thread
#define STAGE(BI, T) do {                                                     \
    const int jb_ = (T) * 32;                                                 \
    _Pragma("unroll")                                                         \
    for (int c_ = 0; c_ < 2; ++c_) {                                          \
        const int cb_ = c_ * 512 + tid;                                       \
        const int r_ = cb_ >> 2;                                              \
        const int cc_ = (cb_ & 3) ^ ((r_ >> 1) & 3);                          \
        gload_lds16(hb + (size_t)r_ * 16384 + jb_ + cc_ * 8,                  \
                    Hs + (BI) * 8192 + (cb_ << 3));                           \
    } } while (0)

    // issue first H tile now; lands during phase 1
    STAGE(0, 0);

    // er_s init
    *(float2*)(er_s + tid * 2) = *(const float2*)(er2 + (b << 10) + tid * 2);
    asm volatile("s_waitcnt lgkmcnt(0)" ::: "memory");
    __builtin_amdgcn_s_barrier();

    // ---------------- Phase 1: adj stream + online log2-LSE ----------------
    unsigned mw[4];
    float m1 = -3.0e38f, s1 = 0.f;
    const int* arow = adj + (size_t)rg * 1024 + js;
#pragma unroll
    for (int kw = 0; kw < 4; ++kw) {
        unsigned wbits = 0;
#pragma unroll
        for (int j = 0; j < 8; ++j) {
            const int k = kw * 8 + j;
            const int4 av = *(const int4*)(arow + k * 32);
            const float4 erv = *(const float4*)(er_s + js + k * 32);
            float e0 = el2i + erv.x; e0 = fmaxf(e0, ALPHA * e0);
            float e1 = el2i + erv.y; e1 = fmaxf(e1, ALPHA * e1);
            float e2 = el2i + erv.z; e2 = fmaxf(e2, ALPHA * e2);
            float e3 = el2i + erv.w; e3 = fmaxf(e3, ALPHA * e3);
            e0 = av.x > 0 ? e0 : -3.0e38f;
            e1 = av.y > 0 ? e1 : -3.0e38f;
            e2 = av.z > 0 ? e2 : -3.0e38f;
            e3 = av.w > 0 ? e3 : -3.0e38f;
            wbits |= ((av.x > 0 ? 1u : 0u) | (av.y > 0 ? 2u : 0u) |
                      (av.z > 0 ? 4u : 0u) | (av.w > 0 ? 8u : 0u)) << (j * 4);
            const float mc = fmaxf(fmaxf(e0, e1), fmaxf(e2, e3));
            const float nm = fmaxf(m1, mc);
            // bogus +1 terms while m1==-3e38 are annihilated by the
            // exp2f(m1-nm)=0 rescale on the first real value / lane combine
            s1 = s1 * exp2f(m1 - nm) + exp2f(e0 - nm) + exp2f(e1 - nm)
               + exp2f(e2 - nm) + exp2f(e3 - nm);
            m1 = nm;
        }
        mw[kw] = wbits;
    }
    // combine the 8 lanes of this row (lanes (ib&7)*8 .. +7: offsets 1,2,4)
#pragma unroll
    for (int off = 1; off <= 4; off <<= 1) {
        const float mo = __shfl_xor(m1, off);
        const float so = __shfl_xor(s1, off);
        const float nm = fmaxf(m1, mo);
        s1 = s1 * exp2f(m1 - nm) + so * exp2f(mo - nm);
        m1 = nm;
    }
    if ((tid & 7) == 0) c_s[ib] = m1 + log2f(s1);
    asm volatile("s_waitcnt lgkmcnt(0)" ::: "memory");
    __builtin_amdgcn_s_barrier();
    const float c2i = c_s[ib];

    // ---------------- Phase 2: 2-phase PV j-loop ----------------
    f32x4 acc[2][4];
#pragma unroll
    for (int i = 0; i < 2; ++i)
#pragma unroll
        for (int j = 0; j < 4; ++j) {
            f32x4 z = {0.f, 0.f, 0.f, 0.f};
            acc[i][j] = z;
        }

#define BUILDR(BI, T) do {                                                    \
    const int jb_ = (T) * 32;                                                 \
    const float4 ev_ = *(const float4*)(er_s + jb_ + js);                     \
    const unsigned mv_ = (mw[(T) >> 3] >> (((T) & 7) * 4)) & 0xFu;            \
    float e0_ = el2i + ev_.x; e0_ = fmaxf(e0_, ALPHA * e0_);                  \
    float e1_ = el2i + ev_.y; e1_ = fmaxf(e1_, ALPHA * e1_);                  \
    float e2_ = el2i + ev_.z; e2_ = fmaxf(e2_, ALPHA * e2_);                  \
    float e3_ = el2i + ev_.w; e3_ = fmaxf(e3_, ALPHA * e3_);                  \
    ushort4 pv_;                                                              \
    pv_.x = (mv_ & 1u) ? f2bf(exp2f(e0_ - c2i)) : (unsigned short)0;          \
    pv_.y = (mv_ & 2u) ? f2bf(exp2f(e1_ - c2i)) : (unsigned short)0;          \
    pv_.z = (mv_ & 4u) ? f2bf(exp2f(e2_ - c2i)) : (unsigned short)0;          \
    pv_.w = (mv_ & 8u) ? f2bf(exp2f(e3_ - c2i)) : (unsigned short)0;          \
    *(ushort4*)(Ps + (BI) * 2560 + ib * 40 + js) = pv_;                       \
    } while (0)

#define COMPUTE(BI) do {                                                      \
    bf16x8 aF_[2], bF_[4];                                                    \
    _Pragma("unroll")                                                         \
    for (int mt_ = 0; mt_ < 2; ++mt_)                                         \
        aF_[mt_] = *(const bf16x8*)(Ps + (BI) * 2560 +                        \
                                    (wm + mt_ * 16 + ml) * 40 + q * 8);       \
    _Pragma("unroll")                                                         \
    for (int nt_ = 0; nt_ < 4; ++nt_) {                                       \
        const int oc_ = wn + nt_ * 16 + ml;                                   \
        const int sl_ = q ^ ((oc_ >> 1) & 3);                                 \
        bF_[nt_] = *(const bf16x8*)(Hs + (BI) * 8192 + oc_ * 32 + sl_ * 8);   \
    }                                                                         \
    _Pragma("unroll")                                                         \
    for (int mt_ = 0; mt_ < 2; ++mt_)                                         \
        _Pragma("unroll")                                                     \
        for (int nt_ = 0; nt_ < 4; ++nt_)                                     \
            acc[mt_][nt_] = __builtin_amdgcn_mfma_f32_16x16x32_bf16(          \
                aF_[mt_], bF_[nt_], acc[mt_][nt_], 0, 0, 0);                  \
    } while (0)

#pragma unroll
    for (int t = 0; t < 32; ++t) {
        const int cur = t & 1;
        if (t + 1 < 32) STAGE((t + 1) & 1, t + 1);
        BUILDR(cur, t);
        if (t + 1 < 32)
            asm volatile("s_waitcnt vmcnt(2) lgkmcnt(0)" ::: "memory");
        else
            asm volatile("s_waitcnt vmcnt(0) lgkmcnt(0)" ::: "memory");
        __builtin_amdgcn_s_barrier();
        __builtin_amdgcn_sched_barrier(0);
        COMPUTE(cur);
        asm volatile("s_waitcnt lgkmcnt(0)" ::: "memory");
        __builtin_amdgcn_s_barrier();
    }

#undef STAGE
#undef BUILDR
#undef COMPUTE

    // D layout: col=lane&15, row=(lane>>4)*4+reg
    float* ob = out + (size_t)b * 262144;
#pragma unroll
    for (int mt = 0; mt < 2; ++mt)
#pragma unroll
        for (int nt = 0; nt < 4; ++nt) {
            const int gn = wn + nt * 16 + ml;
#pragma unroll
            for (int r = 0; r < 4; ++r) {
                const int gm = i0 + wm + mt * 16 + q * 4 + r;
                ob[(size_t)gm * 256 + gn] = acc[mt][nt][r];
            }
        }
}

// ---------------------------------------------------------------------------
// Workspace (~17 MB):
//   Wtbf (bf16) @ 0        : 131072
//   wa   (f32)  @ 131072   : 2048
//   xbf  (bf16) @ 133120   : 8388608   (16384 x 256)
//   h_T  (bf16) @ 8521728  : 8388608   (256 x 16384)
//   el2  (f32)  @ 16910336 : 65536    (log2-scaled)
//   er2  (f32)  @ 16975872 : 65536    (log2-scaled)
// ---------------------------------------------------------------------------
extern "C" void kernel_launch(void* const* d_in, const int* in_sizes, int n_in,
                              void* d_out, int out_size, void* d_ws, size_t ws_size,
                              hipStream_t stream) {
    const float* x   = (const float*)d_in[0];   // (16,1024,256) fp32
    const int*   adj = (const int*)d_in[1];     // (16,1024,1024) int32
    const float* W   = (const float*)d_in[2];   // (256,256) fp32
    const float* a   = (const float*)d_in[3];   // (512,1) fp32
    float* out = (float*)d_out;                 // (16,1024,256) fp32

    char* ws = (char*)d_ws;
    unsigned short* Wtbf  = (unsigned short*)(ws);
    float* wa             = (float*)(ws + 131072);
    unsigned short* xbf   = (unsigned short*)(ws + 133120);
    unsigned short* h_T   = (unsigned short*)(ws + 8521728);
    float* el             = (float*)(ws + 16910336);
    float* er             = (float*)(ws + 16975872);

    wt_wa_kernel<<<dim3(257), dim3(256), 0, stream>>>(W, a, Wtbf, wa);

    eler2x_kernel<<<dim3(4096), dim3(256), 0, stream>>>(x, wa, el, er, xbf);

    // h_T (256 x 16384) = Wtbf @ xbf^T
    gemm_h<<<dim3(128, 4), dim3(256), 0, stream>>>(Wtbf, xbf, h_T);

    maskpv_kernel<<<dim3(256), dim3(512), 0, stream>>>(adj, el, er, h_T, out);
}

// Round 5
// 153.470 us; speedup vs baseline: 1.1052x; 1.1052x over previous
//
#include <hip/hip_runtime.h>
#include <stdint.h>

#define ALPHA 0.2f
#define NEG_BIG -9000000000000000.0f
#define L2E 1.4426950408889634f

typedef __attribute__((ext_vector_type(8))) short bf16x8;
typedef __attribute__((ext_vector_type(8))) unsigned short u16x8;
typedef __attribute__((ext_vector_type(4))) float f32x4;

__device__ __forceinline__ unsigned short f2bf(float f) {
    unsigned int u = __float_as_uint(f);
    u += 0x7fffu + ((u >> 16) & 1u);   // RNE
    return (unsigned short)(u >> 16);
}

__device__ __forceinline__ void gload_lds16(const void* g, void* l) {
    __builtin_amdgcn_global_load_lds(
        (const __attribute__((address_space(1))) unsigned int*)g,
        (__attribute__((address_space(3))) unsigned int*)l, 16, 0, 0);
}

// ---------------------------------------------------------------------------
// Blocks 0..255: Wtbf[o*256+t] = bf16(W[t*256+o]).
// Block 256:     wa[k] = W[k,:]·a_l ; wa[256+k] = W[k,:]·a_r  (fp32).
// ---------------------------------------------------------------------------
__global__ void wt_wa_kernel(const float* __restrict__ W,
                             const float* __restrict__ a,
                             unsigned short* __restrict__ Wtbf,
                             float* __restrict__ wa) {
    const int t = threadIdx.x;
    if (blockIdx.x < 256) {
        const int o = blockIdx.x;
        Wtbf[o * 256 + t] = f2bf(W[t * 256 + o]);
    } else {
        float sl = 0.f, sr = 0.f;
        const float* wr = W + t * 256;
        for (int o = 0; o < 256; ++o) {
            const float wv = wr[o];
            sl += wv * a[o];
            sr += wv * a[256 + o];
        }
        wa[t] = sl;
        wa[256 + t] = sr;
    }
}

// ---------------------------------------------------------------------------
// One wave per row r: el2[r] = (x[r,:]·wa_l)*log2(e), er2 likewise,
// and xbf[r,:] = bf16(x[r,:]).
// ---------------------------------------------------------------------------
__global__ __launch_bounds__(256) void eler2x_kernel(
    const float* __restrict__ x, const float* __restrict__ wa,
    float* __restrict__ el, float* __restrict__ er,
    unsigned short* __restrict__ xbf)
{
    const int w = threadIdx.x >> 6, l = threadIdx.x & 63;
    const int r = blockIdx.x * 4 + w;       // 0..16383
    const float4 xv = *(const float4*)(x + (size_t)r * 256 + l * 4);
    const float4 al = *(const float4*)(wa + l * 4);
    const float4 ar = *(const float4*)(wa + 256 + l * 4);

    ushort4 xb;
    xb.x = f2bf(xv.x); xb.y = f2bf(xv.y); xb.z = f2bf(xv.z); xb.w = f2bf(xv.w);
    *(ushort4*)(xbf + (size_t)r * 256 + l * 4) = xb;

    float sl = xv.x * al.x + xv.y * al.y + xv.z * al.z + xv.w * al.w;
    float sr = xv.x * ar.x + xv.y * ar.y + xv.z * ar.z + xv.w * ar.w;
#pragma unroll
    for (int off = 32; off >= 1; off >>= 1) {
        sl += __shfl_xor(sl, off);
        sr += __shfl_xor(sr, off);
    }
    if (l == 0) { el[r] = sl * L2E; er[r] = sr * L2E; }
}

// ---------------------------------------------------------------------------
// h_T (256 x 16384) = Wtbf (256x256) @ xbf^T.  Flat batched GEMM.
// 64(m) x 128(n) tiles, K-step 64, grid (128,4) = 512 blocks (2/CU).
// 2-phase: double-buffered LDS, counted vmcnt (loads fly across barriers).
// ---------------------------------------------------------------------------
__global__ __launch_bounds__(256) void gemm_h(
    const unsigned short* __restrict__ A,    // Wtbf 256x256
    const unsigned short* __restrict__ Bt,   // xbf 16384x256
    unsigned short* __restrict__ C)          // h_T 256x16384
{
    __shared__ __align__(16) unsigned short As[2 * 64 * 64];    // 16 KB
    __shared__ __align__(16) unsigned short Bs[2 * 128 * 64];   // 32 KB

    const int tid = threadIdx.x;
    const int w = tid >> 6, l = tid & 63;
    const int q = l >> 4, ml = l & 15;
    const int wm = (w >> 1) * 32;
    const int wn = (w & 1) * 64;
    const int m0 = blockIdx.y * 64;
    const int n0 = blockIdx.x * 128;

    f32x4 acc[2][4];
#pragma unroll
    for (int i = 0; i < 2; ++i)
#pragma unroll
        for (int j = 0; j < 4; ++j) {
            f32x4 z = {0.f, 0.f, 0.f, 0.f};
            acc[i][j] = z;
        }

#define GSTAGE(BI, K0) do {                                                   \
    _Pragma("unroll")                                                         \
    for (int c_ = 0; c_ < 2; ++c_) {                                          \
        const int cb_ = c_ * 256 + (w << 6);                                  \
        const int p_ = cb_ + l;                                               \
        const int r_ = p_ >> 3;                                               \
        const int cc_ = (p_ & 7) ^ (r_ & 7);                                  \
        gload_lds16(A + (size_t)(m0 + r_) * 256 + (K0) + cc_ * 8,             \
                    As + (BI) * 4096 + cb_ * 8);                              \
    }                                                                         \
    _Pragma("unroll")                                                         \
    for (int c_ = 0; c_ < 4; ++c_) {                                          \
        const int cb_ = c_ * 256 + (w << 6);                                  \
        const int p_ = cb_ + l;                                               \
        const int r_ = p_ >> 3;                                               \
        const int cc_ = (p_ & 7) ^ (r_ & 7);                                  \
        gload_lds16(Bt + (size_t)(n0 + r_) * 256 + (K0) + cc_ * 8,            \
                    Bs + (BI) * 8192 + cb_ * 8);                              \
    } } while (0)

    GSTAGE(0, 0);

    for (int s = 0; s < 4; ++s) {
        const int cur = s & 1;
        if (s + 1 < 4) {
            GSTAGE((s + 1) & 1, (s + 1) * 64);
            asm volatile("s_waitcnt vmcnt(6) lgkmcnt(0)" ::: "memory");
        } else {
            asm volatile("s_waitcnt vmcnt(0) lgkmcnt(0)" ::: "memory");
        }
        __builtin_amdgcn_s_barrier();
        __builtin_amdgcn_sched_barrier(0);

        const unsigned short* Ab = As + cur * 4096;
        const unsigned short* Bb = Bs + cur * 8192;
        bf16x8 aF[2][2], bF[2][4];
#pragma unroll
        for (int ks = 0; ks < 2; ++ks) {
#pragma unroll
            for (int mt = 0; mt < 2; ++mt) {
                const int mm = wm + mt * 16 + ml;
                aF[ks][mt] = *(const bf16x8*)(Ab + (mm * 8 + ((ks * 4 + q) ^ (mm & 7))) * 8);
            }
#pragma unroll
            for (int nt = 0; nt < 4; ++nt) {
                const int nn = wn + nt * 16 + ml;
                bF[ks][nt] = *(const bf16x8*)(Bb + (nn * 8 + ((ks * 4 + q) ^ (nn & 7))) * 8);
            }
        }
#pragma unroll
        for (int ks = 0; ks < 2; ++ks)
            for (int mt = 0; mt < 2; ++mt)
                for (int nt = 0; nt < 4; ++nt)
                    acc[mt][nt] = __builtin_amdgcn_mfma_f32_16x16x32_bf16(
                        aF[ks][mt], bF[ks][nt], acc[mt][nt], 0, 0, 0);

        asm volatile("s_waitcnt lgkmcnt(0)" ::: "memory");
        __builtin_amdgcn_s_barrier();
    }
#undef GSTAGE

    for (int mt = 0; mt < 2; ++mt)
        for (int nt = 0; nt < 4; ++nt) {
            const int gn = n0 + wn + nt * 16 + ml;
            for (int r = 0; r < 4; ++r) {
                const int gm = m0 + wm + mt * 16 + q * 4 + r;
                C[(size_t)gm * 16384 + gn] = f2bf(acc[mt][nt][r]);
            }
        }
}

// ---------------------------------------------------------------------------
// FUSED mask + PV: out[b, i0..i0+31, :] = softmax(mask(e)) @ h[b].
// Grid 512 (2 blocks/CU), 512 threads (8 waves: 2m x 4n), M = 32 rows/block.
// LDS 77 KB -> 2 blocks/CU = 16 waves/CU = 4/SIMD (round-4 was 1 blk, 2/SIMD,
// Occupancy 18% and latency-bound: VALUBusy 30%, MfmaUtil 5%).
//
// Thread t owns row ib = t>>4, cols {js + 64k, k=0..15}, js = (t&15)*4 —
// identical mapping in all phases; adjacency bits live in 2 registers.
//   Phase 1a: adj stream -> mask bits + row-max ONLY (fmax tree, no
//             transcendentals, no serial rescale chain).
//   Phase 1b: recompute e, sum exp2(e - m) with 4 INDEPENDENT accumulators.
//   (round-4's online-LSE was a 32-deep serial chain of 5 exp2 each — the
//    measured latency wall.)
//   Phase 2: j-step 64 (16 iters): Hs dbuf (2x32 KB) via global_load_lds,
//            gemm_h's proven cc^(r&7) swizzle, counted vmcnt(4), raw
//            barriers; P rebuilt from mask regs + er_s + c_s.
// First Hs stage issued before phase 1 -> latency hidden under adj scan.
// XCD decode: b = ((bid&7)<<1)|(slot>>5): 2 batches (1 MB h) per XCD L2.
// ---------------------------------------------------------------------------
__global__ __launch_bounds__(512) void maskpv_kernel(
    const int* __restrict__ adj,
    const float* __restrict__ el2,
    const float* __restrict__ er2,
    const unsigned short* __restrict__ hT,   // 256 x 16384 (row stride 16384)
    float* __restrict__ out)
{
    __shared__ float er_s[1024];                                  //  4 KB
    __shared__ float c_s[32];
    __shared__ __align__(16) unsigned short Hs[2 * 256 * 64];     // 64 KB
    __shared__ __align__(16) unsigned short Ps[2 * 32 * 72];      //  9 KB

    const int tid = threadIdx.x;
    const int w = tid >> 6, l = tid & 63;
    const int q = l >> 4, ml = l & 15;
    const int wm = (w >> 2) * 16;       // 0 | 16
    const int wn = (w & 3) * 64;        // 0..192

    const int bid = blockIdx.x;
    const int slot = bid >> 3;                        // 0..63
    const int b = ((bid & 7) << 1) | (slot >> 5);     // 2 batches per XCD
    const int i0 = (slot & 31) * 32;

    const int ib = tid >> 4;            // my row (0..31)
    const int js = (tid & 15) * 4;      // my col offset within 64-window
    const int rg = (b << 10) + i0 + ib;
    const float el2i = el2[rg];

    const unsigned short* hb = hT + (size_t)b * 1024;

// stage 32 KB: 2048 chunks of 16B, 512 threads -> 4 gload/thread
#define STAGE(BI, T) do {                                                     \
    const int jb_ = (T) * 64;                                                 \
    _Pragma("unroll")                                                         \
    for (int c_ = 0; c_ < 4; ++c_) {                                          \
        const int cb_ = c_ * 512 + tid;                                       \
        const int r_ = cb_ >> 3;                                              \
        const int cc_ = (cb_ & 7) ^ (r_ & 7);                                 \
        gload_lds16(hb + (size_t)r_ * 16384 + jb_ + cc_ * 8,                  \
                    Hs + (BI) * 16384 + (cb_ << 3));                          \
    } } while (0)

    // issue first H tile now; lands during phase 1
    STAGE(0, 0);

    // er_s init
    *(float2*)(er_s + tid * 2) = *(const float2*)(er2 + (b << 10) + tid * 2);
    asm volatile("s_waitcnt lgkmcnt(0)" ::: "memory");
    __builtin_amdgcn_s_barrier();

    // ------------- Phase 1a: adj stream -> bits + row max (no exp2) --------
    unsigned mw0 = 0, mw1 = 0;
    float m1 = -3.0e38f;
    const int* arow = adj + (size_t)rg * 1024 + js;
#pragma unroll
    for (int k = 0; k < 16; ++k) {
        const int4 av = *(const int4*)(arow + k * 64);
        const float4 erv = *(const float4*)(er_s + k * 64 + js);
        float e0 = el2i + erv.x; e0 = fmaxf(e0, ALPHA * e0);
        float e1 = el2i + erv.y; e1 = fmaxf(e1, ALPHA * e1);
        float e2 = el2i + erv.z; e2 = fmaxf(e2, ALPHA * e2);
        float e3 = el2i + erv.w; e3 = fmaxf(e3, ALPHA * e3);
        const unsigned bits = (av.x > 0 ? 1u : 0u) | (av.y > 0 ? 2u : 0u) |
                              (av.z > 0 ? 4u : 0u) | (av.w > 0 ? 8u : 0u);
        e0 = av.x > 0 ? e0 : -3.0e38f;
        e1 = av.y > 0 ? e1 : -3.0e38f;
        e2 = av.z > 0 ? e2 : -3.0e38f;
        e3 = av.w > 0 ? e3 : -3.0e38f;
        m1 = fmaxf(m1, fmaxf(fmaxf(e0, e1), fmaxf(e2, e3)));
        if (k < 8) mw0 |= bits << (k * 4); else mw1 |= bits << ((k - 8) * 4);
    }
    // row max across the 16 lanes of this row
#pragma unroll
    for (int off = 1; off <= 8; off <<= 1) m1 = fmaxf(m1, __shfl_xor(m1, off));

    // ------------- Phase 1b: independent exp2 accumulation -----------------
    float s0 = 0.f, s1 = 0.f, s2 = 0.f, s3 = 0.f;
#pragma unroll
    for (int k = 0; k < 16; ++k) {
        const float4 erv = *(const float4*)(er_s + k * 64 + js);
        const unsigned mv = ((k < 8) ? (mw0 >> (k * 4)) : (mw1 >> ((k - 8) * 4))) & 0xFu;
        float e0 = el2i + erv.x; e0 = fmaxf(e0, ALPHA * e0);
        float e1 = el2i + erv.y; e1 = fmaxf(e1, ALPHA * e1);
        float e2 = el2i + erv.z; e2 = fmaxf(e2, ALPHA * e2);
        float e3 = el2i + erv.w; e3 = fmaxf(e3, ALPHA * e3);
        s0 += (mv & 1u) ? exp2f(e0 - m1) : 0.f;
        s1 += (mv & 2u) ? exp2f(e1 - m1) : 0.f;
        s2 += (mv & 4u) ? exp2f(e2 - m1) : 0.f;
        s3 += (mv & 8u) ? exp2f(e3 - m1) : 0.f;
    }
    float ssum = (s0 + s1) + (s2 + s3);
#pragma unroll
    for (int off = 1; off <= 8; off <<= 1) ssum += __shfl_xor(ssum, off);
    if ((tid & 15) == 0) c_s[ib] = m1 + log2f(ssum);
    asm volatile("s_waitcnt lgkmcnt(0)" ::: "memory");
    __builtin_amdgcn_s_barrier();
    const float c2i = c_s[ib];

    // ---------------- Phase 2: 2-phase PV j-loop (16 x 64-wide) ------------
    f32x4 acc[4];
#pragma unroll
    for (int j = 0; j < 4; ++j) {
        f32x4 z = {0.f, 0.f, 0.f, 0.f};
        acc[j] = z;
    }

#define BUILDR(BI, T) do {                                                    \
    const float4 ev_ = *(const float4*)(er_s + (T) * 64 + js);                \
    const unsigned mv_ =                                                      \
        (((T) < 8) ? (mw0 >> ((T) * 4)) : (mw1 >> (((T) - 8) * 4))) & 0xFu;   \
    float e0_ = el2i + ev_.x; e0_ = fmaxf(e0_, ALPHA * e0_);                  \
    float e1_ = el2i + ev_.y; e1_ = fmaxf(e1_, ALPHA * e1_);                  \
    float e2_ = el2i + ev_.z; e2_ = fmaxf(e2_, ALPHA * e2_);                  \
    float e3_ = el2i + ev_.w; e3_ = fmaxf(e3_, ALPHA * e3_);                  \
    ushort4 pv_;                                                              \
    pv_.x = (mv_ & 1u) ? f2bf(exp2f(e0_ - c2i)) : (unsigned short)0;          \
    pv_.y = (mv_ & 2u) ? f2bf(exp2f(e1_ - c2i)) : (unsigned short)0;          \
    pv_.z = (mv_ & 4u) ? f2bf(exp2f(e2_ - c2i)) : (unsigned short)0;          \
    pv_.w = (mv_ & 8u) ? f2bf(exp2f(e3_ - c2i)) : (unsigned short)0;          \
    *(ushort4*)(Ps + (BI) * 2304 + ib * 72 + js) = pv_;                       \
    } while (0)

#define COMPUTE(BI) do {                                                      \
    bf16x8 aF_[2], bF_[2][4];                                                 \
    _Pragma("unroll")                                                         \
    for (int ks_ = 0; ks_ < 2; ++ks_)                                         \
        aF_[ks_] = *(const bf16x8*)(Ps + (BI) * 2304 +                        \
                                    (wm + ml) * 72 + ks_ * 32 + q * 8);       \
    _Pragma("unroll")                                                         \
    for (int ks_ = 0; ks_ < 2; ++ks_)                                         \
        _Pragma("unroll")                                                     \
        for (int nt_ = 0; nt_ < 4; ++nt_) {                                   \
            const int oc_ = wn + nt_ * 16 + ml;                               \
            const int sl_ = (ks_ * 4 + q) ^ (oc_ & 7);                        \
            bF_[ks_][nt_] = *(const bf16x8*)(Hs + (BI) * 16384 +              \
                                             oc_ * 64 + sl_ * 8);             \
        }                                                                     \
    _Pragma("unroll")                                                         \
    for (int ks_ = 0; ks_ < 2; ++ks_)                                         \
        _Pragma("unroll")                                                     \
        for (int nt_ = 0; nt_ < 4; ++nt_)                                     \
            acc[nt_] = __builtin_amdgcn_mfma_f32_16x16x32_bf16(               \
                aF_[ks_], bF_[ks_][nt_], acc[nt_], 0, 0, 0);                  \
    } while (0)

#pragma unroll
    for (int t = 0; t < 16; ++t) {
        const int cur = t & 1;
        if (t + 1 < 16) STAGE((t + 1) & 1, t + 1);
        BUILDR(cur, t);
        if (t + 1 < 16)
            asm volatile("s_waitcnt vmcnt(4) lgkmcnt(0)" ::: "memory");
        else
            asm volatile("s_waitcnt vmcnt(0) lgkmcnt(0)" ::: "memory");
        __builtin_amdgcn_s_barrier();
        __builtin_amdgcn_sched_barrier(0);
        COMPUTE(cur);
        asm volatile("s_waitcnt lgkmcnt(0)" ::: "memory");
        __builtin_amdgcn_s_barrier();
    }

#undef STAGE
#undef BUILDR
#undef COMPUTE

    // D layout: col=lane&15, row=(lane>>4)*4+reg
    float* ob = out + (size_t)b * 262144;
#pragma unroll
    for (int nt = 0; nt < 4; ++nt) {
        const int gn = wn + nt * 16 + ml;
#pragma unroll
        for (int r = 0; r < 4; ++r) {
            const int gm = i0 + wm + q * 4 + r;
            ob[(size_t)gm * 256 + gn] = acc[nt][r];
        }
    }
}

// ---------------------------------------------------------------------------
// Workspace (~17 MB):
//   Wtbf (bf16) @ 0        : 131072
//   wa   (f32)  @ 131072   : 2048
//   xbf  (bf16) @ 133120   : 8388608   (16384 x 256)
//   h_T  (bf16) @ 8521728  : 8388608   (256 x 16384)
//   el2  (f32)  @ 16910336 : 65536    (log2-scaled)
//   er2  (f32)  @ 16975872 : 65536    (log2-scaled)
// ---------------------------------------------------------------------------
extern "C" void kernel_launch(void* const* d_in, const int* in_sizes, int n_in,
                              void* d_out, int out_size, void* d_ws, size_t ws_size,
                              hipStream_t stream) {
    const float* x   = (const float*)d_in[0];   // (16,1024,256) fp32
    const int*   adj = (const int*)d_in[1];     // (16,1024,1024) int32
    const float* W   = (const float*)d_in[2];   // (256,256) fp32
    const float* a   = (const float*)d_in[3];   // (512,1) fp32
    float* out = (float*)d_out;                 // (16,1024,256) fp32

    char* ws = (char*)d_ws;
    unsigned short* Wtbf  = (unsigned short*)(ws);
    float* wa             = (float*)(ws + 131072);
    unsigned short* xbf   = (unsigned short*)(ws + 133120);
    unsigned short* h_T   = (unsigned short*)(ws + 8521728);
    float* el             = (float*)(ws + 16910336);
    float* er             = (float*)(ws + 16975872);

    wt_wa_kernel<<<dim3(257), dim3(256), 0, stream>>>(W, a, Wtbf, wa);

    eler2x_kernel<<<dim3(4096), dim3(256), 0, stream>>>(x, wa, el, er, xbf);

    // h_T (256 x 16384) = Wtbf @ xbf^T
    gemm_h<<<dim3(128, 4), dim3(256), 0, stream>>>(Wtbf, xbf, h_T);

    maskpv_kernel<<<dim3(512), dim3(512), 0, stream>>>(adj, el, er, h_T, out);
}